// Round 7
// baseline (78.894 us; speedup 1.0000x reference)
//
#include <hip/hip_runtime.h>

#define N_BATCH 128
#define W_RAW   128
#define NSEG    (W_RAW - 1)             // 127 raw segments
#define W_UP    1024
#define TPB     256
#define QCHUNK  8                       // query chunks per (n,dir); 128 queries/block
#define QPB     128
#define SCHUNK  4                       // segment chunks (= wave id, wave-uniform)
#define SPC     32                      // segments per chunk (last chunk has 31)
#define NBLK    (N_BATCH * 2 * QCHUNK)  // 2048 blocks -> 8 blocks/CU, 32 waves/CU

// ws layout (floats): partS[2048] | partP[2048] | partD[2048] | widx[2*128*1024] (int)
#define WS_S 0
#define WS_P 2048
#define WS_D 4096
#define WS_I 6144

__device__ __forceinline__ void interp_setup(int i, int& i0, int& i1, float& w, float& w0) {
    const double step = 127.0 / 1023.0;       // align_corners=True linspace step (f64, np-like)
    double pos = (double)i * step;
    i0 = (int)pos;
    if (i0 > W_RAW - 1) i0 = W_RAW - 1;
    i1 = min(i0 + 1, W_RAW - 1);
    w  = (float)(pos - (double)i0);
    w0 = __fsub_rn(1.0f, w);
}

__global__ __launch_bounds__(TPB, 8) void chamfer_kernel(
    const float* __restrict__ tp,   // target_points   (N, 2, 128)
    const float* __restrict__ pr,   // predictions     (N, 2, 128)
    const float* __restrict__ vm,   // visibility_mask (N, 128)
    float* __restrict__ ws)
{
    __shared__ float2 s_c[W_UP];            // interpolated candidate curve (8 KB)
    __shared__ float4 s_segA[NSEG];         // Kx, Ky, b, s*1023/127 + 0.5 (~2 KB)
    __shared__ float2 s_segB[NSEG];         // lo_f, hi_f (integer-valued) (~1 KB)
    __shared__ float  s_pd[SCHUNK][QPB];    // per-chunk best distance     (2 KB)
    __shared__ int    s_pi[SCHUNK][QPB];    // per-chunk best index; row 0 reused as merged (2 KB)
    __shared__ float  s_red[4 * 3];

    const int bid    = blockIdx.x;
    const int qchunk = bid & (QCHUNK - 1);
    const int dir    = (bid >> 3) & 1;      // 0: query=t cand=p ; 1: query=p cand=t
    const int n      = bid >> 4;
    const int tid    = threadIdx.x;
    const int nd     = n * 2 + dir;

    const float* q_base = (dir == 0) ? tp : pr;
    const float* c_base = (dir == 0) ? pr : tp;
    const float* qx_raw = q_base + (size_t)(n * 2 + 0) * W_RAW;
    const float* qy_raw = q_base + (size_t)(n * 2 + 1) * W_RAW;
    const float* cx_raw = c_base + (size_t)(n * 2 + 0) * W_RAW;
    const float* cy_raw = c_base + (size_t)(n * 2 + 1) * W_RAW;
    const float* m_raw  = vm + (size_t)n * W_RAW;

    // stage full candidate curve (4 points/thread), bit-exact interp
    #pragma unroll
    for (int k = 0; k < W_UP / TPB; ++k) {
        const int i = tid + k * TPB;
        int i0, i1; float w, w0;
        interp_setup(i, i0, i1, w, w0);
        const float cx = __fadd_rn(__fmul_rn(cx_raw[i0], w0), __fmul_rn(cx_raw[i1], w));
        const float cy = __fadd_rn(__fmul_rn(cy_raw[i0], w0), __fmul_rn(cy_raw[i1], w));
        s_c[i] = make_float2(cx, cy);
    }

    // per-segment projection precompute: t(q) = dot(q,K)+b is the line
    // parameter; round(s8 + t*1023/127) clamped to [lo,hi] is the in-range
    // integer argmin of the exact distance parabola over candidate indices.
    // (t-clamp folded into the float ic-clamp; bounds are exact integers.)
    if (tid < NSEG) {
        const int s = tid;
        const float ax = cx_raw[s],     ay = cy_raw[s];
        const float bx = cx_raw[s + 1], by = cy_raw[s + 1];
        const float abx = bx - ax, aby = by - ay;
        const float len2 = abx * abx + aby * aby;
        const float inv  = (len2 > 0.0f) ? (1.0f / len2) : 0.0f;
        const float Kx = abx * inv, Ky = aby * inv;
        const float bb = -(ax * abx + ay * aby) * inv;
        const float s8h = (float)s * (1023.0f / 127.0f) + 0.5f;  // +0.5: round via trunc
        s_segA[s] = make_float4(Kx, Ky, bb, s8h);
        s_segB[s] = make_float2((float)((s * 1023 + 126) / 127),
                                (float)(((s + 1) * 1023) / 127));
    }

    // scan-phase mapping: 64 query-groups x 4 segment-chunks (chunk = wave id)
    const int jc = tid >> 6;
    const int g  = tid & 63;

    float qx[2], qy[2];
    #pragma unroll
    for (int k = 0; k < 2; ++k) {
        const int qi = qchunk * QPB + g * 2 + k;
        int i0, i1; float w, w0;
        interp_setup(qi, i0, i1, w, w0);
        qx[k] = __fadd_rn(__fmul_rn(qx_raw[i0], w0), __fmul_rn(qx_raw[i1], w));
        qy[k] = __fadd_rn(__fmul_rn(qy_raw[i0], w0), __fmul_rn(qy_raw[i1], w));
    }
    __syncthreads();

    float bestd[2];
    int   bidx[2];
    #pragma unroll
    for (int k = 0; k < 2; ++k) { bestd[k] = 3.4e38f; bidx[k] = 0; }

    const int sbase = jc * SPC;
    const int send  = min(sbase + SPC, NSEG);
    #pragma unroll 4
    for (int s = sbase; s < send; ++s) {
        const float4 SA = s_segA[s];   // wave-uniform -> broadcast
        const float2 SB = s_segB[s];
        #pragma unroll
        for (int k = 0; k < 2; ++k) {
            const float t  = __builtin_fmaf(qy[k], SA.y, __builtin_fmaf(qx[k], SA.x, SA.z));
            float ic = __builtin_fmaf(t, 1023.0f / 127.0f, SA.w);
            ic = fminf(fmaxf(ic, SB.x), SB.y);   // -> v_med3_f32
            const int i0 = (int)ic;              // trunc of (x+0.5) == round, ic >= 0
            const float2 c0 = s_c[i0];
            // exact f32 distance form (matches numpy bit-for-bit)
            const float dx0 = __fsub_rn(qx[k], c0.x);
            const float dy0 = __fsub_rn(qy[k], c0.y);
            const float d0  = __fadd_rn(__fmul_rn(dx0, dx0), __fmul_rn(dy0, dy0));
            // ascending index order + strict '<' == numpy first-occurrence
            const bool lt = d0 < bestd[k];
            bestd[k] = lt ? d0 : bestd[k];
            bidx[k]  = lt ? i0 : bidx[k];
        }
    }

    #pragma unroll
    for (int k = 0; k < 2; ++k) {
        const int q = g * 2 + k;
        s_pd[jc][q] = bestd[k];
        s_pi[jc][q] = bidx[k];
    }
    __syncthreads();

    // merge + epilogue: one query per thread, threads 0..QPB-1 only.
    float S = 0.0f, P = 0.0f, D = 0.0f;
    if (tid < QPB) {
        float bd = s_pd[0][tid];
        int   bi = s_pi[0][tid];
        #pragma unroll
        for (int c = 1; c < SCHUNK; ++c) {
            const float d2 = s_pd[c][tid];
            const bool lt = d2 < bd;
            bd = lt ? d2 : bd;
            bi = lt ? s_pi[c][tid] : bi;
        }
        s_pi[0][tid] = bi;   // column-local read-then-write: safe reuse as merged

        const int qi = qchunk * QPB + tid;
        ((int*)(ws + WS_I))[(size_t)nd * W_UP + qi] = bi;   // for boundary patch

        int i0m, i1m; float wm, w0m;
        interp_setup(qi, i0m, i1m, wm, w0m);
        const float qxm = __fadd_rn(__fmul_rn(qx_raw[i0m], w0m), __fmul_rn(qx_raw[i1m], wm));
        const float qym = __fadd_rn(__fmul_rn(qy_raw[i0m], w0m), __fmul_rn(qy_raw[i1m], wm));
        const float mv  = __fadd_rn(__fmul_rn(m_raw[i0m], w0m), __fmul_rn(m_raw[i1m], wm));
        const float mq  = (mv < 0.5f) ? 0.0f : mv;          // jnp.where(m < 0.5, 0, m)

        S = bd * mq;
        if (dir == 0) {   // direct (aligned) error, once per batch row
            const float2 c = s_c[qi];
            const float dx = qxm - c.x;
            const float dy = qym - c.y;
            D = (dx * dx + dy * dy) * mq;
        }
        __syncthreads();
        // order penalty, block-internal pairs; boundary pairs patched in finalize
        if (tid < QPB - 1) {
            const float df = (float)(s_pi[0][tid] - s_pi[0][tid + 1]);
            const float r  = fmaxf(df, 0.0f);
            P = r * r * mq;
        }
    } else {
        __syncthreads();
    }

    // block reduction
    #pragma unroll
    for (int off = 32; off > 0; off >>= 1) {
        S += __shfl_down(S, off, 64);
        P += __shfl_down(P, off, 64);
        D += __shfl_down(D, off, 64);
    }
    const int wave = tid >> 6, lane = tid & 63;
    if (lane == 0) {
        s_red[wave * 3 + 0] = S;
        s_red[wave * 3 + 1] = P;
        s_red[wave * 3 + 2] = D;
    }
    __syncthreads();
    if (tid == 0) {
        float St = 0.f, Pt = 0.f, Dt = 0.f;
        #pragma unroll
        for (int w2 = 0; w2 < TPB / 64; ++w2) {
            St += s_red[w2 * 3 + 0];
            Pt += s_red[w2 * 3 + 1];
            Dt += s_red[w2 * 3 + 2];
        }
        ws[WS_S + bid] = St;
        ws[WS_P + bid] = Pt;
        ws[WS_D + bid] = Dt;   // 0 for dir==1 blocks
    }
}

__global__ __launch_bounds__(TPB) void finalize_kernel(
    const float* __restrict__ vm,
    const float* __restrict__ ws,
    float* __restrict__ out)
{
    __shared__ float s_red[4 * 3];
    const int tid = threadIdx.x;

    float S = 0.f, P = 0.f, D = 0.f;
    #pragma unroll
    for (int k = 0; k < NBLK / TPB; ++k) {
        const int b = tid + k * TPB;
        S += ws[WS_S + b];
        P += ws[WS_P + b];
        D += ws[WS_D + b];
    }

    // chunk-boundary penalty pairs: 7 per (n,dir) at i = b*128-1, b in 1..7
    for (int idx = tid; idx < N_BATCH * 2 * (QCHUNK - 1); idx += TPB) {  // 1792
        const int nd = idx / (QCHUNK - 1);         // n*2+dir
        const int b  = idx % (QCHUNK - 1) + 1;
        const int i  = b * QPB - 1;
        const int n  = nd >> 1;
        const int* widx = (const int*)(ws + WS_I) + (size_t)nd * W_UP;
        const float df = (float)(widx[i] - widx[i + 1]);
        const float r  = fmaxf(df, 0.0f);
        int i0, i1; float w, w0;
        interp_setup(i, i0, i1, w, w0);
        const float* m_raw = vm + (size_t)n * W_RAW;
        float mv = __fadd_rn(__fmul_rn(m_raw[i0], w0), __fmul_rn(m_raw[i1], w));
        const float mq = (mv < 0.5f) ? 0.0f : mv;
        P += r * r * mq;
    }

    #pragma unroll
    for (int off = 32; off > 0; off >>= 1) {
        S += __shfl_down(S, off, 64);
        P += __shfl_down(P, off, 64);
        D += __shfl_down(D, off, 64);
    }
    const int wave = tid >> 6, lane = tid & 63;
    if (lane == 0) {
        s_red[wave * 3 + 0] = S;
        s_red[wave * 3 + 1] = P;
        s_red[wave * 3 + 2] = D;
    }
    __syncthreads();
    if (tid == 0) {
        float St = 0.f, Pt = 0.f, Dt = 0.f;
        #pragma unroll
        for (int w2 = 0; w2 < TPB / 64; ++w2) {
            St += s_red[w2 * 3 + 0];
            Pt += s_red[w2 * 3 + 1];
            Dt += s_red[w2 * 3 + 2];
        }
        const float nw  = (float)(N_BATCH * W_UP);         // 131072
        const float nw1 = (float)(N_BATCH * (W_UP - 1));   // 130944
        const float matched = St / (2.0f * nw) + 0.1f * Pt / (2.0f * nw1);
        const float direct  = Dt / nw;
        out[0] = fminf(matched, direct);
    }
}

extern "C" void kernel_launch(void* const* d_in, const int* in_sizes, int n_in,
                              void* d_out, int out_size, void* d_ws, size_t ws_size,
                              hipStream_t stream) {
    const float* tp = (const float*)d_in[0];
    const float* pr = (const float*)d_in[1];
    const float* vm = (const float*)d_in[2];
    float* out = (float*)d_out;
    float* ws  = (float*)d_ws;

    chamfer_kernel<<<NBLK, TPB, 0, stream>>>(tp, pr, vm, ws);
    finalize_kernel<<<1, TPB, 0, stream>>>(vm, ws, out);
}